// Round 21
// baseline (104.776 us; speedup 1.0000x reference)
//
#include <hip/hip_runtime.h>
#include <hip/hip_cooperative_groups.h>
#include <math.h>

// BipolarMorphological2D SMorph as a bf16 MFMA GEMM (R21).
// delta-form: e^kf = 1 + delta -> d = S_m + GEMM(m,delta); n = S_mlm + GEMM(..)
//   M = 7200 (s*2+sign), N = 256 (o*4+tbl), K = 576 (c*2+{m,mlm} per 3x3 pos)
// R21 vs R17: SINGLE cooperative kernel (prep -> grid.sync -> gemm) to kill
// the inter-dispatch drain. Grid 225 blocks x 512 thr (co-resident on 256
// CUs; launch_bounds(512,2) -> VGPR<=256). Phase1: grid-stride prep (pixs +
// pixm + bt). Phase2: R17's exact gemm re-indexed: bm=blockIdx.x, 8 waves =
// kq2 x nq4, wave = 32Mx64Nx9 steps; load counts identical to R17 (97K).
// K-combine LDS tree + epilogue transpose + store, as proven in R15-R17.

namespace cg = cooperative_groups;

typedef float  f32x4 __attribute__((ext_vector_type(4)));
typedef short  s16x8 __attribute__((ext_vector_type(8)));

#define BB   4
#define CC   32
#define HH   32
#define WW   32
#define OO   64
#define HO   30
#define WO   30
#define NSP  900
#define KDIM 576

#define T1   131072            // branch1: pixel sums + pixm pack
#define TB   18432             // branch2: B pack
#define NTHR (225*512)         // fused grid thread count

__device__ __forceinline__ unsigned short f2bf(float f) {
    unsigned u = __float_as_uint(f);
    return (unsigned short)((u + 0x7FFFu + ((u >> 16) & 1u)) >> 16);
}

__global__ __launch_bounds__(512, 2) void smorph_fused(
    const float* __restrict__ x, const float* __restrict__ k1,
    const float* __restrict__ k2, const float* __restrict__ bias,
    float4* __restrict__ pixs, unsigned* __restrict__ pixm,
    unsigned short* __restrict__ bt, float* __restrict__ out)
{
    __shared__ __align__(16) char ldsbuf[34816];
    float* cmb = (float*)ldsbuf;      // 4 slots x 2048 f32 (32 KB)
    float* epi = (float*)ldsbuf;      // 4 slots x 2112 f32, pitch 66 (33.8 KB)

    // ================= phase 1: prep (grid-stride) =================
    for (int t = blockIdx.x*512 + threadIdx.x; t < T1 + TB; t += NTHR) {
        if (t < T1) {
            const int pix = t >> 5, c = t & 31;
            const int b = pix >> 10, h = (pix >> 5) & 31, w = pix & 31;
            float v = x[b*32768 + c*1024 + h*32 + w];
            float mp = fmaxf(v, 0.1f), mn = fmaxf(-v, 0.1f);
            float lp = mp * logf(mp), ln_ = mn * logf(mn);
            pixm[pix*64      + c] = (unsigned)f2bf(mp) | ((unsigned)f2bf(lp)  << 16);
            pixm[pix*64 + 32 + c] = (unsigned)f2bf(mn) | ((unsigned)f2bf(ln_) << 16);
            float s0 = mp, s1 = lp, s2 = mn, s3 = ln_;
#pragma unroll
            for (int m = 16; m >= 1; m >>= 1) {
                s0 += __shfl_xor(s0, m); s1 += __shfl_xor(s1, m);
                s2 += __shfl_xor(s2, m); s3 += __shfl_xor(s3, m);
            }
            if (c == 0) pixs[pix] = make_float4(s0, s1, s2, s3);
        } else {
            const int u3 = t - T1;
            const int o = u3 & 63, p = u3 >> 6;
            const float a = k1[u3], b2 = k2[u3];
            const float d1 = expm1f(a),  q1 = a  * expf(a);
            const float d2 = expm1f(b2), q2 = b2 * expf(b2);
            const float vals[4][2] = {{d1, 0.f}, {q1, d1}, {d2, 0.f}, {q2, d2}};
#pragma unroll
            for (int tbl = 0; tbl < 4; ++tbl) {
                const int n = o*4 + tbl;
#pragma unroll
                for (int ks = 0; ks < 2; ++ks) {
                    const int k    = 2*p + ks;
                    const int st   = k >> 5, k32 = k & 31;
                    const int lane = (n & 15) + ((k32 >> 3) << 4);
                    bt[((n >> 4)*18 + st)*512 + lane*8 + (k32 & 7)] = f2bf(vals[tbl][ks]);
                }
            }
        }
    }

    __threadfence();               // device-scope release of pixs/pixm/bt
    cg::this_grid().sync();        // all prep visible to all XCDs

    // ================= phase 2: GEMM (R17 body, re-indexed) =================
    const int tid = threadIdx.x;
    const int l   = tid & 63;
    const int w   = tid >> 6;                  // wave 0..7
    const int kq  = w >> 2;                    // K-half (step parity)
    const int nq  = w & 3;                     // N-quarter (64 cols)
    const int bm  = blockIdx.x;                // M-tile (16 s, 32 rows)
    const int ng0 = nq*4;

    const int lr = l & 15;
    const int lg = l >> 4;

    // per-lane fp32 window sums (store waves only)
    float4 S = make_float4(0,0,0,0);
    if (kq == 0) {
        const int s  = bm*16 + lr;
        const int b  = s / NSP, r = s - b*NSP;
        const int ho = r / WO,  wo = r - WO*(r/WO);
        const float4* P = pixs + (b*1024 + ho*32 + wo);
#pragma unroll
        for (int kh = 0; kh < 3; ++kh)
#pragma unroll
            for (int kw = 0; kw < 3; ++kw) {
                float4 v = P[kh*32 + kw];
                S.x += v.x; S.y += v.y; S.z += v.z; S.w += v.w;
            }
    }

    // A lane byte-offsets into pixm: pix*256 + sign*128 + lg*16
    unsigned offA[2];
    {
        const int sign = lr & 1;
#pragma unroll
        for (int mi = 0; mi < 2; ++mi) {
            const int s  = bm*16 + mi*8 + (lr >> 1);
            const int b  = s / NSP, r = s - b*NSP;
            const int ho = r / WO,  wo = r - WO*(r/WO);
            const int pix = b*1024 + ho*32 + wo;
            offA[mi] = (unsigned)(pix*256 + sign*128 + lg*16);
        }
    }

    const char* pa = (const char*)pixm;
    const char* pb = (const char*)bt;

    f32x4 acc[2][4] = {};

#pragma unroll
    for (int s2 = 0; s2 < 9; ++s2) {
        const int step  = s2*2 + kq;           // this wave's 9 steps
        const int khkw  = step >> 1;
        const int kh    = khkw / 3, kw = khkw - 3*(khkw/3);
        const unsigned immA = (unsigned)(kh*8192 + kw*256 + (step & 1)*64);

        s16x8 a0 = *(const s16x8*)(pa + (offA[0] + immA));
        s16x8 a1 = *(const s16x8*)(pa + (offA[1] + immA));
        s16x8 b0 = *(const s16x8*)(pb + (((ng0+0)*18 + step)*64 + l)*16);
        s16x8 b1 = *(const s16x8*)(pb + (((ng0+1)*18 + step)*64 + l)*16);
        s16x8 b2 = *(const s16x8*)(pb + (((ng0+2)*18 + step)*64 + l)*16);
        s16x8 b3 = *(const s16x8*)(pb + (((ng0+3)*18 + step)*64 + l)*16);

        acc[0][0] = __builtin_amdgcn_mfma_f32_16x16x32_bf16(a0, b0, acc[0][0], 0, 0, 0);
        acc[0][1] = __builtin_amdgcn_mfma_f32_16x16x32_bf16(a0, b1, acc[0][1], 0, 0, 0);
        acc[0][2] = __builtin_amdgcn_mfma_f32_16x16x32_bf16(a0, b2, acc[0][2], 0, 0, 0);
        acc[0][3] = __builtin_amdgcn_mfma_f32_16x16x32_bf16(a0, b3, acc[0][3], 0, 0, 0);
        acc[1][0] = __builtin_amdgcn_mfma_f32_16x16x32_bf16(a1, b0, acc[1][0], 0, 0, 0);
        acc[1][1] = __builtin_amdgcn_mfma_f32_16x16x32_bf16(a1, b1, acc[1][1], 0, 0, 0);
        acc[1][2] = __builtin_amdgcn_mfma_f32_16x16x32_bf16(a1, b2, acc[1][2], 0, 0, 0);
        acc[1][3] = __builtin_amdgcn_mfma_f32_16x16x32_bf16(a1, b3, acc[1][3], 0, 0, 0);
    }

    __syncthreads();   // phase-1 LDS (none) / ensure all waves past prep

    // ---- K-combine: kq1 -> cmb[nq] (r-major, conflict-free), kq0 adds
    if (kq == 1) {
        float* dst = cmb + nq*2048 + l;
#pragma unroll
        for (int mi = 0; mi < 2; ++mi)
#pragma unroll
            for (int ni = 0; ni < 4; ++ni)
#pragma unroll
                for (int r = 0; r < 4; ++r)
                    dst[((mi*4 + ni)*4 + r)*64] = acc[mi][ni][r];
    }
    __syncthreads();
    if (kq == 0) {
        const float* srcp = cmb + nq*2048 + l;
#pragma unroll
        for (int mi = 0; mi < 2; ++mi)
#pragma unroll
            for (int ni = 0; ni < 4; ++ni)
#pragma unroll
                for (int r = 0; r < 4; ++r)
                    acc[mi][ni][r] += srcp[((mi*4 + ni)*4 + r)*64];
    }
    __syncthreads();   // cmb consumed; reuse as epi
    if (kq == 0) {
        // epilogue write: rows lg*4+r (+16 per mi), cols ni*16+lr, pitch 66
        float* E = epi + nq*2112;
        const int wrbase = lg*4*66 + lr;
#pragma unroll
        for (int mi = 0; mi < 2; ++mi)
#pragma unroll
            for (int ni = 0; ni < 4; ++ni)
#pragma unroll
                for (int r = 0; r < 4; ++r)
                    E[wrbase + (mi*16 + r)*66 + ni*16] = acc[mi][ni][r];
    }
    __syncthreads();

    if (kq == 0) {
        const float* E = epi + nq*2112;
        const int sl = lr;
        const int s  = bm*16 + sl;
        const int b  = s / NSP;
        const int r900 = s - b*NSP;
#pragma unroll
        for (int oi = 0; oi < 4; ++oi) {
            int ol = lg*4 + oi;
            int o  = nq*16 + ol;
            float4 v0 = *(const float4*)&E[(2*sl + 0)*66 + ol*4];  // pos: d1,n1,d2,n2
            float4 v1 = *(const float4*)&E[(2*sl + 1)*66 + ol*4];  // neg
            float d1p = S.x + v0.x, n1p = S.y + v0.y;
            float d2p = S.x + v0.z, n2p = S.y + v0.w;
            float d1n = S.z + v1.x, n1n = S.w + v1.y;
            float d2n = S.z + v1.z, n2n = S.w + v1.w;
            float P = __expf(n1p/d1p) - __expf(n2p/d2p)
                    - __expf(n1n/d1n) + __expf(n2n/d2n);
            out[((size_t)(b*OO + o))*NSP + r900] = P + bias[o];
        }
    }
}

extern "C" void kernel_launch(void* const* d_in, const int* in_sizes, int n_in,
                              void* d_out, int out_size, void* d_ws, size_t ws_size,
                              hipStream_t stream) {
    const float* x    = (const float*)d_in[0];
    const float* k1   = (const float*)d_in[1];
    const float* k2   = (const float*)d_in[2];
    const float* bias = (const float*)d_in[3];

    char* ws = (char*)d_ws;
    float4*         pixs = (float4*)(ws);                    // 64 KB
    unsigned*       pixm = (unsigned*)(ws + 0x10000);        // 1 MB
    unsigned short* bt   = (unsigned short*)(ws + 0x110000); // 294,912 B
    float*          outp = (float*)d_out;

    void* args[] = { (void*)&x, (void*)&k1, (void*)&k2, (void*)&bias,
                     (void*)&pixs, (void*)&pixm, (void*)&bt, (void*)&outp };
    hipLaunchCooperativeKernel((const void*)smorph_fused, dim3(225), dim3(512),
                               args, 0, stream);
}

// Round 22
// 19.861 us; speedup vs baseline: 5.2754x; 5.2754x over previous
//
#include <hip/hip_runtime.h>
#include <math.h>

// BipolarMorphological2D SMorph as a bf16 MFMA GEMM (R22 = R17 + __logf prep).
// delta-form: e^kf = 1 + delta -> d = S_m + GEMM(m,delta); n = S_mlm + GEMM(..)
//   M = 7200 (s*2+sign), N = 256 (o*4+tbl), K = 576 (c*2+{m,mlm} per 3x3 pos)
// R17 structure (best known, 19.75us): prep writes unique bf16 table
// pixm[pix][sign][c] (1MB) + fp32 window-sum source pixs + frag-packed B;
// gemm = 450 blocks x 4 waves (kq2 x nhf2), wave = 32Mx64Nx9 steps, A direct
// from pixm (offA+immA, 16 lines/instr), B lane-linear, K-split-2 LDS combine
// + epilogue transpose. R22 change: branch-1 logf -> __logf (hw v_log_f32;
// feeds bf16 packs + fp32 sums, rel-err 1e-5 is far inside the 1.16e-3 budget).

typedef float  f32x4 __attribute__((ext_vector_type(4)));
typedef short  s16x8 __attribute__((ext_vector_type(8)));

#define BB   4
#define CC   32
#define HH   32
#define WW   32
#define OO   64
#define HO   30
#define WO   30
#define NSP  900
#define KDIM 576

#define T1   131072            // branch1: pixel sums + pixm pack
#define TB   18432             // branch2: B pack

__device__ __forceinline__ unsigned short f2bf(float f) {
    unsigned u = __float_as_uint(f);
    return (unsigned short)((u + 0x7FFFu + ((u >> 16) & 1u)) >> 16);
}

// ---- prep: pixs[pix] = fp32 c-sums (Smp, Smlmp, Smn, Smlmn)
//            pixm[pix*64 + sign*32 + c] = packed bf16 (m | mlm<<16)
//            bt: bf16 B in MFMA-frag order: [ng(16)][step(18)][lane(64)] x 16B
__global__ __launch_bounds__(256) void smorph_prep(
    const float* __restrict__ x, const float* __restrict__ k1,
    const float* __restrict__ k2, float4* __restrict__ pixs,
    unsigned* __restrict__ pixm, unsigned short* __restrict__ bt)
{
    const int t = blockIdx.x * 256 + threadIdx.x;

    if (t < T1) {
        const int pix = t >> 5, c = t & 31;
        const int b = pix >> 10, h = (pix >> 5) & 31, w = pix & 31;
        float v = x[b*32768 + c*1024 + h*32 + w];
        float mp = fmaxf(v, 0.1f), mn = fmaxf(-v, 0.1f);
        float lp = mp * __logf(mp), ln_ = mn * __logf(mn);
        pixm[pix*64      + c] = (unsigned)f2bf(mp) | ((unsigned)f2bf(lp)  << 16);
        pixm[pix*64 + 32 + c] = (unsigned)f2bf(mn) | ((unsigned)f2bf(ln_) << 16);
        float s0 = mp, s1 = lp, s2 = mn, s3 = ln_;
#pragma unroll
        for (int m = 16; m >= 1; m >>= 1) {
            s0 += __shfl_xor(s0, m); s1 += __shfl_xor(s1, m);
            s2 += __shfl_xor(s2, m); s3 += __shfl_xor(s3, m);
        }
        if (c == 0) pixs[pix] = make_float4(s0, s1, s2, s3);
    } else if (t < T1 + TB) {
        const int u3 = t - T1;
        const int o = u3 & 63, p = u3 >> 6;
        const float a = k1[u3], b2 = k2[u3];
        const float d1 = expm1f(a),  q1 = a  * expf(a);
        const float d2 = expm1f(b2), q2 = b2 * expf(b2);
        const float vals[4][2] = {{d1, 0.f}, {q1, d1}, {d2, 0.f}, {q2, d2}};
#pragma unroll
        for (int tbl = 0; tbl < 4; ++tbl) {
            const int n = o*4 + tbl;
#pragma unroll
            for (int ks = 0; ks < 2; ++ks) {
                const int k    = 2*p + ks;
                const int st   = k >> 5, k32 = k & 31;
                const int lane = (n & 15) + ((k32 >> 3) << 4);
                bt[((n >> 4)*18 + st)*512 + lane*8 + (k32 & 7)] = f2bf(vals[tbl][ks]);
            }
        }
    }
}

// ---- GEMM: 450 blocks x 256 thr (4 waves: kq x nhf). Wave: 32M x 64N x 9 steps.
__global__ __launch_bounds__(256, 2) void smorph_gemm(
    const unsigned* __restrict__ pixm, const unsigned short* __restrict__ bt,
    const float4* __restrict__ pixs, const float* __restrict__ bias,
    float* __restrict__ out)
{
    __shared__ float cmb[2][2048];               // 16 KB: K-combine, r-major
    __shared__ __align__(16) float epi[2][32*66];// 16.9 KB: epilogue transpose

    const int tid = threadIdx.x;
    const int l   = tid & 63;
    const int w   = tid >> 6;                  // wave 0..3
    const int kq  = w >> 1;                    // K-half (step parity)
    const int nhf = w & 1;                     // N-half within block
    const int bm  = blockIdx.x >> 1;           // M-tile (16 s, 32 rows)
    const int nh  = blockIdx.x & 1;
    const int N0  = nh*128 + nhf*64;
    const int ng0 = N0 >> 4;

    const int lr = l & 15;
    const int lg = l >> 4;

    // ---- per-lane fp32 window sums (epilogue only)
    float4 S;
    {
        const int s  = bm*16 + lr;
        const int b  = s / NSP, r = s - b*NSP;
        const int ho = r / WO,  wo = r - WO*(r/WO);
        const float4* P = pixs + (b*1024 + ho*32 + wo);
        float4 a = make_float4(0,0,0,0);
#pragma unroll
        for (int kh = 0; kh < 3; ++kh)
#pragma unroll
            for (int kw = 0; kw < 3; ++kw) {
                float4 v = P[kh*32 + kw];
                a.x += v.x; a.y += v.y; a.z += v.z; a.w += v.w;
            }
        S = a;
    }

    // A lane byte-offsets into pixm: pix*256 + sign*128 + lg*16
    unsigned offA[2];
    {
        const int sign = lr & 1;
#pragma unroll
        for (int mi = 0; mi < 2; ++mi) {
            const int s  = bm*16 + mi*8 + (lr >> 1);
            const int b  = s / NSP, r = s - b*NSP;
            const int ho = r / WO,  wo = r - WO*(r/WO);
            const int pix = b*1024 + ho*32 + wo;
            offA[mi] = (unsigned)(pix*256 + sign*128 + lg*16);
        }
    }

    const char* pa = (const char*)pixm;
    const char* pb = (const char*)bt;

    f32x4 acc[2][4] = {};

#pragma unroll
    for (int s2 = 0; s2 < 9; ++s2) {
        const int step  = s2*2 + kq;           // this wave's 9 steps
        const int khkw  = step >> 1;
        const int kh    = khkw / 3, kw = khkw - 3*(khkw/3);
        const int khalf = step & 1;
        const unsigned immA = (unsigned)(kh*8192 + kw*256 + khalf*64);

        s16x8 a0 = *(const s16x8*)(pa + (offA[0] + immA));   // L2-hot, 16 lines
        s16x8 a1 = *(const s16x8*)(pa + (offA[1] + immA));
        s16x8 b0 = *(const s16x8*)(pb + (((ng0+0)*18 + step)*64 + l)*16);  // lane-linear
        s16x8 b1 = *(const s16x8*)(pb + (((ng0+1)*18 + step)*64 + l)*16);
        s16x8 b2 = *(const s16x8*)(pb + (((ng0+2)*18 + step)*64 + l)*16);
        s16x8 b3 = *(const s16x8*)(pb + (((ng0+3)*18 + step)*64 + l)*16);

        acc[0][0] = __builtin_amdgcn_mfma_f32_16x16x32_bf16(a0, b0, acc[0][0], 0, 0, 0);
        acc[0][1] = __builtin_amdgcn_mfma_f32_16x16x32_bf16(a0, b1, acc[0][1], 0, 0, 0);
        acc[0][2] = __builtin_amdgcn_mfma_f32_16x16x32_bf16(a0, b2, acc[0][2], 0, 0, 0);
        acc[0][3] = __builtin_amdgcn_mfma_f32_16x16x32_bf16(a0, b3, acc[0][3], 0, 0, 0);
        acc[1][0] = __builtin_amdgcn_mfma_f32_16x16x32_bf16(a1, b0, acc[1][0], 0, 0, 0);
        acc[1][1] = __builtin_amdgcn_mfma_f32_16x16x32_bf16(a1, b1, acc[1][1], 0, 0, 0);
        acc[1][2] = __builtin_amdgcn_mfma_f32_16x16x32_bf16(a1, b2, acc[1][2], 0, 0, 0);
        acc[1][3] = __builtin_amdgcn_mfma_f32_16x16x32_bf16(a1, b3, acc[1][3], 0, 0, 0);
    }

    // ---- K-combine: kq1 -> LDS (r-major, conflict-free), kq0 adds
    if (kq == 1) {
#pragma unroll
        for (int mi = 0; mi < 2; ++mi)
#pragma unroll
            for (int ni = 0; ni < 4; ++ni)
#pragma unroll
                for (int r = 0; r < 4; ++r)
                    cmb[nhf][(mi*16 + ni*4 + r)*64 + l] = acc[mi][ni][r];
    }
    __syncthreads();
    if (kq == 0) {
#pragma unroll
        for (int mi = 0; mi < 2; ++mi)
#pragma unroll
            for (int ni = 0; ni < 4; ++ni)
#pragma unroll
                for (int r = 0; r < 4; ++r)
                    acc[mi][ni][r] += cmb[nhf][(mi*16 + ni*4 + r)*64 + l];

        // epilogue write: acc -> epi[nhf] [row 0..31][col 0..63], pitch 66
        const int wrbase = lg*4*66 + lr;
#pragma unroll
        for (int mi = 0; mi < 2; ++mi)
#pragma unroll
            for (int ni = 0; ni < 4; ++ni)
#pragma unroll
                for (int r = 0; r < 4; ++r)
                    epi[nhf][wrbase + (mi*16 + r)*66 + ni*16] = acc[mi][ni][r];
    }
    __syncthreads();

    if (kq == 0) {
        const int sl = lr;
        const int s  = bm*16 + sl;
        const int b  = s / NSP;
        const int r900 = s - b*NSP;
#pragma unroll
        for (int oi = 0; oi < 4; ++oi) {
            int ol = lg*4 + oi;
            int o  = (N0 >> 2) + ol;
            float4 v0 = *(const float4*)&epi[nhf][(2*sl + 0)*66 + ol*4];  // pos
            float4 v1 = *(const float4*)&epi[nhf][(2*sl + 1)*66 + ol*4];  // neg
            float d1p = S.x + v0.x, n1p = S.y + v0.y;
            float d2p = S.x + v0.z, n2p = S.y + v0.w;
            float d1n = S.z + v1.x, n1n = S.w + v1.y;
            float d2n = S.z + v1.z, n2n = S.w + v1.w;
            float P = __expf(n1p/d1p) - __expf(n2p/d2p)
                    - __expf(n1n/d1n) + __expf(n2n/d2n);
            out[((size_t)(b*OO + o))*NSP + r900] = P + bias[o];
        }
    }
}

extern "C" void kernel_launch(void* const* d_in, const int* in_sizes, int n_in,
                              void* d_out, int out_size, void* d_ws, size_t ws_size,
                              hipStream_t stream) {
    const float* x    = (const float*)d_in[0];
    const float* k1   = (const float*)d_in[1];
    const float* k2   = (const float*)d_in[2];
    const float* bias = (const float*)d_in[3];

    char* ws = (char*)d_ws;
    float4*         pixs = (float4*)(ws);                    // 64 KB
    unsigned*       pixm = (unsigned*)(ws + 0x10000);        // 1 MB
    unsigned short* bt   = (unsigned short*)(ws + 0x110000); // 294,912 B
    float*          out  = (float*)d_out;

    hipLaunchKernelGGL(smorph_prep, dim3((T1 + TB + 255)/256), dim3(256), 0, stream,
                       x, k1, k2, pixs, pixm, bt);
    hipLaunchKernelGGL(smorph_gemm, dim3(450), dim3(256), 0, stream,
                       pixm, bt, pixs, bias, out);
}

// Round 23
// 19.559 us; speedup vs baseline: 5.3570x; 1.0155x over previous
//
#include <hip/hip_runtime.h>
#include <math.h>

// BipolarMorphological2D SMorph as a bf16 MFMA GEMM (R23 = R17 + coalesced prep).
// delta-form: e^kf = 1 + delta -> d = S_m + GEMM(m,delta); n = S_mlm + GEMM(..)
//   M = 7200 (s*2+sign), N = 256 (o*4+tbl), K = 576 (c*2+{m,mlm} per 3x3 pos)
// R23 change: prep branch-1 was a 4KB-strided gather (32 lines/wave-load,
// ~65K line requests ~ same order as the gemm's 97K). Now: block = one (b,h),
// coalesced (c,w)-tile load -> LDS [c][33] (pad kills bank conflicts) ->
// re-indexed pixm writes (lane=c, 256B/wave coalesced stores) + c-sum via
// LDS columns + shfl_xor(32) -> coalesced pixs float4 writes.
// Gemm is R17's exact best (19.75us): 450 blocks x 4 waves (kq2 x nhf2),
// A direct from pixm, B lane-linear frag-packed, K-split-2 combine.

typedef float  f32x4 __attribute__((ext_vector_type(4)));
typedef short  s16x8 __attribute__((ext_vector_type(8)));

#define BB   4
#define CC   32
#define HH   32
#define WW   32
#define OO   64
#define HO   30
#define WO   30
#define NSP  900
#define KDIM 576
#define TB   18432             // B-pack items

__device__ __forceinline__ unsigned short f2bf(float f) {
    unsigned u = __float_as_uint(f);
    return (unsigned short)((u + 0x7FFFu + ((u >> 16) & 1u)) >> 16);
}

// ---- prep: grid = 128 pixel-blocks (one per (b,h)) + 72 B-pack blocks
__global__ __launch_bounds__(256) void smorph_prep(
    const float* __restrict__ x, const float* __restrict__ k1,
    const float* __restrict__ k2, float4* __restrict__ pixs,
    unsigned* __restrict__ pixm, unsigned short* __restrict__ bt)
{
    if (blockIdx.x < 128) {
        __shared__ float lmp[32*33], lmn[32*33], llp[32*33], lln[32*33];
        const int b = blockIdx.x >> 5, h = blockIdx.x & 31;
        const int tid = threadIdx.x;

        // phase A: coalesced x load (lanes = consecutive w), compute, LDS store
#pragma unroll
        for (int i = 0; i < 4; ++i) {
            const int u = tid + 256*i;
            const int c = u >> 5, w = u & 31;
            float v = x[b*32768 + c*1024 + h*32 + w];
            float mp = fmaxf(v, 0.1f), mn = fmaxf(-v, 0.1f);
            lmp[c*33 + w] = mp;
            lmn[c*33 + w] = mn;
            llp[c*33 + w] = mp * __logf(mp);
            lln[c*33 + w] = mn * __logf(mn);
        }
        __syncthreads();

        // phase B: pixm writes, lane = c -> fully coalesced 256B/wave stores
        const int pixbase = b*1024 + h*32;
#pragma unroll
        for (int i = 0; i < 8; ++i) {
            const int u    = tid + 256*i;         // 2048 items: w(5b) sign(1b) c(5b)
            const int c    = u & 31;
            const int sign = (u >> 5) & 1;
            const int w    = u >> 6;
            float m  = sign ? lmn[c*33 + w] : lmp[c*33 + w];   // (c+w)%32 banks: conflict-free
            float ml = sign ? lln[c*33 + w] : llp[c*33 + w];
            pixm[(pixbase + w)*64 + sign*32 + c] =
                (unsigned)f2bf(m) | ((unsigned)f2bf(ml) << 16);
        }

        // phase C: c-sums (first wave): lane = hp*32 + w, hp sums 16 c's
        if (tid < 64) {
            const int w  = tid & 31, hp = tid >> 5;
            float s0 = 0.f, s1 = 0.f, s2 = 0.f, s3 = 0.f;
#pragma unroll
            for (int cc = 0; cc < 16; ++cc) {
                const int c = hp*16 + cc;
                s0 += lmp[c*33 + w]; s1 += llp[c*33 + w];
                s2 += lmn[c*33 + w]; s3 += lln[c*33 + w];
            }
            s0 += __shfl_xor(s0, 32); s1 += __shfl_xor(s1, 32);
            s2 += __shfl_xor(s2, 32); s3 += __shfl_xor(s3, 32);
            if (hp == 0) pixs[pixbase + w] = make_float4(s0, s1, s2, s3);
        }
    } else {
        const int t = (blockIdx.x - 128)*256 + threadIdx.x;
        if (t < TB) {
            const int o = t & 63, p = t >> 6;
            const float a = k1[t], b2 = k2[t];
            const float d1 = expm1f(a),  q1 = a  * expf(a);
            const float d2 = expm1f(b2), q2 = b2 * expf(b2);
            const float vals[4][2] = {{d1, 0.f}, {q1, d1}, {d2, 0.f}, {q2, d2}};
#pragma unroll
            for (int tbl = 0; tbl < 4; ++tbl) {
                const int n = o*4 + tbl;
#pragma unroll
                for (int ks = 0; ks < 2; ++ks) {
                    const int k    = 2*p + ks;
                    const int st   = k >> 5, k32 = k & 31;
                    const int lane = (n & 15) + ((k32 >> 3) << 4);
                    bt[((n >> 4)*18 + st)*512 + lane*8 + (k32 & 7)] = f2bf(vals[tbl][ks]);
                }
            }
        }
    }
}

// ---- GEMM: 450 blocks x 256 thr (4 waves: kq x nhf). Wave: 32M x 64N x 9 steps.
__global__ __launch_bounds__(256, 2) void smorph_gemm(
    const unsigned* __restrict__ pixm, const unsigned short* __restrict__ bt,
    const float4* __restrict__ pixs, const float* __restrict__ bias,
    float* __restrict__ out)
{
    __shared__ float cmb[2][2048];               // 16 KB: K-combine, r-major
    __shared__ __align__(16) float epi[2][32*66];// 16.9 KB: epilogue transpose

    const int tid = threadIdx.x;
    const int l   = tid & 63;
    const int w   = tid >> 6;                  // wave 0..3
    const int kq  = w >> 1;                    // K-half (step parity)
    const int nhf = w & 1;                     // N-half within block
    const int bm  = blockIdx.x >> 1;           // M-tile (16 s, 32 rows)
    const int nh  = blockIdx.x & 1;
    const int N0  = nh*128 + nhf*64;
    const int ng0 = N0 >> 4;

    const int lr = l & 15;
    const int lg = l >> 4;

    // ---- per-lane fp32 window sums (epilogue only)
    float4 S;
    {
        const int s  = bm*16 + lr;
        const int b  = s / NSP, r = s - b*NSP;
        const int ho = r / WO,  wo = r - WO*(r/WO);
        const float4* P = pixs + (b*1024 + ho*32 + wo);
        float4 a = make_float4(0,0,0,0);
#pragma unroll
        for (int kh = 0; kh < 3; ++kh)
#pragma unroll
            for (int kw = 0; kw < 3; ++kw) {
                float4 v = P[kh*32 + kw];
                a.x += v.x; a.y += v.y; a.z += v.z; a.w += v.w;
            }
        S = a;
    }

    // A lane byte-offsets into pixm: pix*256 + sign*128 + lg*16
    unsigned offA[2];
    {
        const int sign = lr & 1;
#pragma unroll
        for (int mi = 0; mi < 2; ++mi) {
            const int s  = bm*16 + mi*8 + (lr >> 1);
            const int b  = s / NSP, r = s - b*NSP;
            const int ho = r / WO,  wo = r - WO*(r/WO);
            const int pix = b*1024 + ho*32 + wo;
            offA[mi] = (unsigned)(pix*256 + sign*128 + lg*16);
        }
    }

    const char* pa = (const char*)pixm;
    const char* pb = (const char*)bt;

    f32x4 acc[2][4] = {};

#pragma unroll
    for (int s2 = 0; s2 < 9; ++s2) {
        const int step  = s2*2 + kq;           // this wave's 9 steps
        const int khkw  = step >> 1;
        const int kh    = khkw / 3, kw = khkw - 3*(khkw/3);
        const int khalf = step & 1;
        const unsigned immA = (unsigned)(kh*8192 + kw*256 + khalf*64);

        s16x8 a0 = *(const s16x8*)(pa + (offA[0] + immA));   // L2-hot, 16 lines
        s16x8 a1 = *(const s16x8*)(pa + (offA[1] + immA));
        s16x8 b0 = *(const s16x8*)(pb + (((ng0+0)*18 + step)*64 + l)*16);  // lane-linear
        s16x8 b1 = *(const s16x8*)(pb + (((ng0+1)*18 + step)*64 + l)*16);
        s16x8 b2 = *(const s16x8*)(pb + (((ng0+2)*18 + step)*64 + l)*16);
        s16x8 b3 = *(const s16x8*)(pb + (((ng0+3)*18 + step)*64 + l)*16);

        acc[0][0] = __builtin_amdgcn_mfma_f32_16x16x32_bf16(a0, b0, acc[0][0], 0, 0, 0);
        acc[0][1] = __builtin_amdgcn_mfma_f32_16x16x32_bf16(a0, b1, acc[0][1], 0, 0, 0);
        acc[0][2] = __builtin_amdgcn_mfma_f32_16x16x32_bf16(a0, b2, acc[0][2], 0, 0, 0);
        acc[0][3] = __builtin_amdgcn_mfma_f32_16x16x32_bf16(a0, b3, acc[0][3], 0, 0, 0);
        acc[1][0] = __builtin_amdgcn_mfma_f32_16x16x32_bf16(a1, b0, acc[1][0], 0, 0, 0);
        acc[1][1] = __builtin_amdgcn_mfma_f32_16x16x32_bf16(a1, b1, acc[1][1], 0, 0, 0);
        acc[1][2] = __builtin_amdgcn_mfma_f32_16x16x32_bf16(a1, b2, acc[1][2], 0, 0, 0);
        acc[1][3] = __builtin_amdgcn_mfma_f32_16x16x32_bf16(a1, b3, acc[1][3], 0, 0, 0);
    }

    // ---- K-combine: kq1 -> LDS (r-major, conflict-free), kq0 adds
    if (kq == 1) {
#pragma unroll
        for (int mi = 0; mi < 2; ++mi)
#pragma unroll
            for (int ni = 0; ni < 4; ++ni)
#pragma unroll
                for (int r = 0; r < 4; ++r)
                    cmb[nhf][(mi*16 + ni*4 + r)*64 + l] = acc[mi][ni][r];
    }
    __syncthreads();
    if (kq == 0) {
#pragma unroll
        for (int mi = 0; mi < 2; ++mi)
#pragma unroll
            for (int ni = 0; ni < 4; ++ni)
#pragma unroll
                for (int r = 0; r < 4; ++r)
                    acc[mi][ni][r] += cmb[nhf][(mi*16 + ni*4 + r)*64 + l];

        // epilogue write: acc -> epi[nhf] [row 0..31][col 0..63], pitch 66
        const int wrbase = lg*4*66 + lr;
#pragma unroll
        for (int mi = 0; mi < 2; ++mi)
#pragma unroll
            for (int ni = 0; ni < 4; ++ni)
#pragma unroll
                for (int r = 0; r < 4; ++r)
                    epi[nhf][wrbase + (mi*16 + r)*66 + ni*16] = acc[mi][ni][r];
    }
    __syncthreads();

    if (kq == 0) {
        const int sl = lr;
        const int s  = bm*16 + sl;
        const int b  = s / NSP;
        const int r900 = s - b*NSP;
#pragma unroll
        for (int oi = 0; oi < 4; ++oi) {
            int ol = lg*4 + oi;
            int o  = (N0 >> 2) + ol;
            float4 v0 = *(const float4*)&epi[nhf][(2*sl + 0)*66 + ol*4];  // pos
            float4 v1 = *(const float4*)&epi[nhf][(2*sl + 1)*66 + ol*4];  // neg
            float d1p = S.x + v0.x, n1p = S.y + v0.y;
            float d2p = S.x + v0.z, n2p = S.y + v0.w;
            float d1n = S.z + v1.x, n1n = S.w + v1.y;
            float d2n = S.z + v1.z, n2n = S.w + v1.w;
            float P = __expf(n1p/d1p) - __expf(n2p/d2p)
                    - __expf(n1n/d1n) + __expf(n2n/d2n);
            out[((size_t)(b*OO + o))*NSP + r900] = P + bias[o];
        }
    }
}

extern "C" void kernel_launch(void* const* d_in, const int* in_sizes, int n_in,
                              void* d_out, int out_size, void* d_ws, size_t ws_size,
                              hipStream_t stream) {
    const float* x    = (const float*)d_in[0];
    const float* k1   = (const float*)d_in[1];
    const float* k2   = (const float*)d_in[2];
    const float* bias = (const float*)d_in[3];

    char* ws = (char*)d_ws;
    float4*         pixs = (float4*)(ws);                    // 64 KB
    unsigned*       pixm = (unsigned*)(ws + 0x10000);        // 1 MB
    unsigned short* bt   = (unsigned short*)(ws + 0x110000); // 294,912 B
    float*          out  = (float*)d_out;

    hipLaunchKernelGGL(smorph_prep, dim3(128 + (TB + 255)/256), dim3(256), 0, stream,
                       x, k1, k2, pixs, pixm, bt);
    hipLaunchKernelGGL(smorph_gemm, dim3(450), dim3(256), 0, stream,
                       pixm, bt, pixs, bias, out);
}

// Round 24
// 19.556 us; speedup vs baseline: 5.3578x; 1.0002x over previous
//
#include <hip/hip_runtime.h>
#include <math.h>

// BipolarMorphological2D SMorph as a bf16 MFMA GEMM (R24 = R23 + full hoist).
// delta-form: e^kf = 1 + delta -> d = S_m + GEMM(m,delta); n = S_mlm + GEMM(..)
//   M = 7200 (s*2+sign), N = 256 (o*4+tbl), K = 576 (c*2+{m,mlm} per 3x3 pos)
// R24 change: gemm issues ALL 54 operand loads up front into 9-slot register
// arrays (216 operand VGPR + 32 acc; launch_bounds(256,1) lifts the 256-VGPR
// cap; occupancy is grid-limited at 1.76 blocks/CU so residency unchanged),
// then runs all 72 MFMAs. MLP 4 -> 54: one L2 round-trip instead of ~9 per
// wave. Model: L2-resident pixm/bt at ~200-400cyc, previous structure was
// serializing on latency with ~2-step compiler lookahead (256-VGPR cap).
// Prep = R23's coalesced version. Epilogue/combine unchanged (R17).

typedef float  f32x4 __attribute__((ext_vector_type(4)));
typedef short  s16x8 __attribute__((ext_vector_type(8)));

#define BB   4
#define CC   32
#define HH   32
#define WW   32
#define OO   64
#define HO   30
#define WO   30
#define NSP  900
#define KDIM 576
#define TB   18432             // B-pack items

__device__ __forceinline__ unsigned short f2bf(float f) {
    unsigned u = __float_as_uint(f);
    return (unsigned short)((u + 0x7FFFu + ((u >> 16) & 1u)) >> 16);
}

// ---- prep: grid = 128 pixel-blocks (one per (b,h)) + 72 B-pack blocks
__global__ __launch_bounds__(256) void smorph_prep(
    const float* __restrict__ x, const float* __restrict__ k1,
    const float* __restrict__ k2, float4* __restrict__ pixs,
    unsigned* __restrict__ pixm, unsigned short* __restrict__ bt)
{
    if (blockIdx.x < 128) {
        __shared__ float lmp[32*33], lmn[32*33], llp[32*33], lln[32*33];
        const int b = blockIdx.x >> 5, h = blockIdx.x & 31;
        const int tid = threadIdx.x;

#pragma unroll
        for (int i = 0; i < 4; ++i) {
            const int u = tid + 256*i;
            const int c = u >> 5, w = u & 31;
            float v = x[b*32768 + c*1024 + h*32 + w];
            float mp = fmaxf(v, 0.1f), mn = fmaxf(-v, 0.1f);
            lmp[c*33 + w] = mp;
            lmn[c*33 + w] = mn;
            llp[c*33 + w] = mp * __logf(mp);
            lln[c*33 + w] = mn * __logf(mn);
        }
        __syncthreads();

        const int pixbase = b*1024 + h*32;
#pragma unroll
        for (int i = 0; i < 8; ++i) {
            const int u    = tid + 256*i;         // w(5b) sign(1b) c(5b)
            const int c    = u & 31;
            const int sign = (u >> 5) & 1;
            const int w    = u >> 6;
            float m  = sign ? lmn[c*33 + w] : lmp[c*33 + w];
            float ml = sign ? lln[c*33 + w] : llp[c*33 + w];
            pixm[(pixbase + w)*64 + sign*32 + c] =
                (unsigned)f2bf(m) | ((unsigned)f2bf(ml) << 16);
        }

        if (tid < 64) {
            const int w  = tid & 31, hp = tid >> 5;
            float s0 = 0.f, s1 = 0.f, s2 = 0.f, s3 = 0.f;
#pragma unroll
            for (int cc = 0; cc < 16; ++cc) {
                const int c = hp*16 + cc;
                s0 += lmp[c*33 + w]; s1 += llp[c*33 + w];
                s2 += lmn[c*33 + w]; s3 += lln[c*33 + w];
            }
            s0 += __shfl_xor(s0, 32); s1 += __shfl_xor(s1, 32);
            s2 += __shfl_xor(s2, 32); s3 += __shfl_xor(s3, 32);
            if (hp == 0) pixs[pixbase + w] = make_float4(s0, s1, s2, s3);
        }
    } else {
        const int t = (blockIdx.x - 128)*256 + threadIdx.x;
        if (t < TB) {
            const int o = t & 63, p = t >> 6;
            const float a = k1[t], b2 = k2[t];
            const float d1 = expm1f(a),  q1 = a  * expf(a);
            const float d2 = expm1f(b2), q2 = b2 * expf(b2);
            const float vals[4][2] = {{d1, 0.f}, {q1, d1}, {d2, 0.f}, {q2, d2}};
#pragma unroll
            for (int tbl = 0; tbl < 4; ++tbl) {
                const int n = o*4 + tbl;
#pragma unroll
                for (int ks = 0; ks < 2; ++ks) {
                    const int k    = 2*p + ks;
                    const int st   = k >> 5, k32 = k & 31;
                    const int lane = (n & 15) + ((k32 >> 3) << 4);
                    bt[((n >> 4)*18 + st)*512 + lane*8 + (k32 & 7)] = f2bf(vals[tbl][ks]);
                }
            }
        }
    }
}

// ---- GEMM: 450 blocks x 256 thr (4 waves: kq x nhf). Wave: 32M x 64N x 9 steps.
// All 54 loads issued up front (9-slot register arrays), then 72 MFMAs.
__global__ __launch_bounds__(256, 1) void smorph_gemm(
    const unsigned* __restrict__ pixm, const unsigned short* __restrict__ bt,
    const float4* __restrict__ pixs, const float* __restrict__ bias,
    float* __restrict__ out)
{
    __shared__ float cmb[2][2048];               // 16 KB: K-combine, r-major
    __shared__ __align__(16) float epi[2][32*66];// 16.9 KB: epilogue transpose

    const int tid = threadIdx.x;
    const int l   = tid & 63;
    const int w   = tid >> 6;                  // wave 0..3
    const int kq  = w >> 1;                    // K-half (step parity)
    const int nhf = w & 1;                     // N-half within block
    const int bm  = blockIdx.x >> 1;           // M-tile (16 s, 32 rows)
    const int nh  = blockIdx.x & 1;
    const int N0  = nh*128 + nhf*64;
    const int ng0 = N0 >> 4;

    const int lr = l & 15;
    const int lg = l >> 4;

    // ---- per-lane fp32 window sums (epilogue only)
    float4 S;
    {
        const int s  = bm*16 + lr;
        const int b  = s / NSP, r = s - b*NSP;
        const int ho = r / WO,  wo = r - WO*(r/WO);
        const float4* P = pixs + (b*1024 + ho*32 + wo);
        float4 a = make_float4(0,0,0,0);
#pragma unroll
        for (int kh = 0; kh < 3; ++kh)
#pragma unroll
            for (int kw = 0; kw < 3; ++kw) {
                float4 v = P[kh*32 + kw];
                a.x += v.x; a.y += v.y; a.z += v.z; a.w += v.w;
            }
        S = a;
    }

    // A lane byte-offsets into pixm: pix*256 + sign*128 + lg*16
    unsigned offA[2];
    {
        const int sign = lr & 1;
#pragma unroll
        for (int mi = 0; mi < 2; ++mi) {
            const int s  = bm*16 + mi*8 + (lr >> 1);
            const int b  = s / NSP, r = s - b*NSP;
            const int ho = r / WO,  wo = r - WO*(r/WO);
            const int pix = b*1024 + ho*32 + wo;
            offA[mi] = (unsigned)(pix*256 + sign*128 + lg*16);
        }
    }

    const char* pa = (const char*)pixm;
    const char* pb = (const char*)bt;

    // ---- issue ALL 54 loads (9 steps x 6 operands) before any MFMA
    s16x8 ra0[9], ra1[9], rb0[9], rb1[9], rb2[9], rb3[9];
#pragma unroll
    for (int s2 = 0; s2 < 9; ++s2) {
        const int step  = s2*2 + kq;
        const int khkw  = step >> 1;
        const int kh    = khkw / 3, kw = khkw - 3*(khkw/3);
        const unsigned immA = (unsigned)(kh*8192 + kw*256 + (step & 1)*64);

        ra0[s2] = *(const s16x8*)(pa + (offA[0] + immA));
        ra1[s2] = *(const s16x8*)(pa + (offA[1] + immA));
        rb0[s2] = *(const s16x8*)(pb + (((ng0+0)*18 + step)*64 + l)*16);
        rb1[s2] = *(const s16x8*)(pb + (((ng0+1)*18 + step)*64 + l)*16);
        rb2[s2] = *(const s16x8*)(pb + (((ng0+2)*18 + step)*64 + l)*16);
        rb3[s2] = *(const s16x8*)(pb + (((ng0+3)*18 + step)*64 + l)*16);
    }

    f32x4 acc[2][4] = {};
#pragma unroll
    for (int s2 = 0; s2 < 9; ++s2) {
        acc[0][0] = __builtin_amdgcn_mfma_f32_16x16x32_bf16(ra0[s2], rb0[s2], acc[0][0], 0, 0, 0);
        acc[0][1] = __builtin_amdgcn_mfma_f32_16x16x32_bf16(ra0[s2], rb1[s2], acc[0][1], 0, 0, 0);
        acc[0][2] = __builtin_amdgcn_mfma_f32_16x16x32_bf16(ra0[s2], rb2[s2], acc[0][2], 0, 0, 0);
        acc[0][3] = __builtin_amdgcn_mfma_f32_16x16x32_bf16(ra0[s2], rb3[s2], acc[0][3], 0, 0, 0);
        acc[1][0] = __builtin_amdgcn_mfma_f32_16x16x32_bf16(ra1[s2], rb0[s2], acc[1][0], 0, 0, 0);
        acc[1][1] = __builtin_amdgcn_mfma_f32_16x16x32_bf16(ra1[s2], rb1[s2], acc[1][1], 0, 0, 0);
        acc[1][2] = __builtin_amdgcn_mfma_f32_16x16x32_bf16(ra1[s2], rb2[s2], acc[1][2], 0, 0, 0);
        acc[1][3] = __builtin_amdgcn_mfma_f32_16x16x32_bf16(ra1[s2], rb3[s2], acc[1][3], 0, 0, 0);
    }

    // ---- K-combine: kq1 -> LDS (r-major, conflict-free), kq0 adds
    if (kq == 1) {
#pragma unroll
        for (int mi = 0; mi < 2; ++mi)
#pragma unroll
            for (int ni = 0; ni < 4; ++ni)
#pragma unroll
                for (int r = 0; r < 4; ++r)
                    cmb[nhf][(mi*16 + ni*4 + r)*64 + l] = acc[mi][ni][r];
    }
    __syncthreads();
    if (kq == 0) {
#pragma unroll
        for (int mi = 0; mi < 2; ++mi)
#pragma unroll
            for (int ni = 0; ni < 4; ++ni)
#pragma unroll
                for (int r = 0; r < 4; ++r)
                    acc[mi][ni][r] += cmb[nhf][(mi*16 + ni*4 + r)*64 + l];

        // epilogue write: acc -> epi[nhf] [row 0..31][col 0..63], pitch 66
        const int wrbase = lg*4*66 + lr;
#pragma unroll
        for (int mi = 0; mi < 2; ++mi)
#pragma unroll
            for (int ni = 0; ni < 4; ++ni)
#pragma unroll
                for (int r = 0; r < 4; ++r)
                    epi[nhf][wrbase + (mi*16 + r)*66 + ni*16] = acc[mi][ni][r];
    }
    __syncthreads();

    if (kq == 0) {
        const int sl = lr;
        const int s  = bm*16 + sl;
        const int b  = s / NSP;
        const int r900 = s - b*NSP;
#pragma unroll
        for (int oi = 0; oi < 4; ++oi) {
            int ol = lg*4 + oi;
            int o  = (N0 >> 2) + ol;
            float4 v0 = *(const float4*)&epi[nhf][(2*sl + 0)*66 + ol*4];  // pos
            float4 v1 = *(const float4*)&epi[nhf][(2*sl + 1)*66 + ol*4];  // neg
            float d1p = S.x + v0.x, n1p = S.y + v0.y;
            float d2p = S.x + v0.z, n2p = S.y + v0.w;
            float d1n = S.z + v1.x, n1n = S.w + v1.y;
            float d2n = S.z + v1.z, n2n = S.w + v1.w;
            float P = __expf(n1p/d1p) - __expf(n2p/d2p)
                    - __expf(n1n/d1n) + __expf(n2n/d2n);
            out[((size_t)(b*OO + o))*NSP + r900] = P + bias[o];
        }
    }
}

extern "C" void kernel_launch(void* const* d_in, const int* in_sizes, int n_in,
                              void* d_out, int out_size, void* d_ws, size_t ws_size,
                              hipStream_t stream) {
    const float* x    = (const float*)d_in[0];
    const float* k1   = (const float*)d_in[1];
    const float* k2   = (const float*)d_in[2];
    const float* bias = (const float*)d_in[3];

    char* ws = (char*)d_ws;
    float4*         pixs = (float4*)(ws);                    // 64 KB
    unsigned*       pixm = (unsigned*)(ws + 0x10000);        // 1 MB
    unsigned short* bt   = (unsigned short*)(ws + 0x110000); // 294,912 B
    float*          out  = (float*)d_out;

    hipLaunchKernelGGL(smorph_prep, dim3(128 + (TB + 255)/256), dim3(256), 0, stream,
                       x, k1, k2, pixs, pixm, bt);
    hipLaunchKernelGGL(smorph_gemm, dim3(450), dim3(256), 0, stream,
                       pixm, bt, pixs, bias, out);
}